// Round 7
// baseline (6867.213 us; speedup 1.0000x reference)
//
#include <hip/hip_runtime.h>
#include <hip/hip_bf16.h>
#include <hip/hip_cooperative_groups.h>

namespace cg = cooperative_groups;

#define SEQ 512
#define BATCH 128
#define INP 512
#define HID 1024
#define CLASSES 1000
#define KTOT (INP + HID)      // 1536
#define NKT (KTOT / 32)       // 48
#define NKX (INP / 32)        // 16
#define NKH (HID / 32)        // 32

#define NBLK 128
#define NTHR 512              // 8 waves, M=16 per wave
#define BJ 8                  // h-columns per block
#define G4H (4 * HID)

typedef float f32x4 __attribute__((ext_vector_type(4)));
typedef short bf16x8 __attribute__((ext_vector_type(8)));

__device__ __forceinline__ short f2bf16s(float f) {
    __hip_bfloat16 h = __float2bfloat16(f);
    return __builtin_bit_cast(short, h);
}
__device__ __forceinline__ float sigmoidf_(float x) {
    return 1.0f / (1.0f + __expf(-x));
}
__device__ __forceinline__ float tanhf_(float x) {
    x = fminf(fmaxf(x, -15.0f), 15.0f);
    float e = __expf(2.0f * x);
    return (e - 1.0f) / (e + 1.0f);
}
__device__ __forceinline__ int permbuf(int t) { return (t * 197) & 511; }

// ================= K1: fp32 -> bf16 convert (x, optionally W_ih) =========
#define XCH (SEQ * BATCH * INP / 8)
#define WCH (4 * HID * INP / 8)
__global__ __launch_bounds__(256)
void convert_bf16(const float* __restrict__ x, const float* __restrict__ W_ih,
                  unsigned short* __restrict__ xbf, unsigned short* __restrict__ Wbf,
                  int do_w) {
    const size_t total = XCH + (do_w ? WCH : 0);
    for (size_t c = (size_t)blockIdx.x * blockDim.x + threadIdx.x; c < total;
         c += (size_t)gridDim.x * blockDim.x) {
        const float* src; unsigned short* dst;
        if (c < XCH) { src = x + c * 8;            dst = xbf + c * 8; }
        else         { src = W_ih + (c - XCH) * 8; dst = Wbf + (c - XCH) * 8; }
        const float4 a = *(const float4*)src;
        const float4 b = *(const float4*)(src + 4);
        bf16x8 v;
        v[0] = f2bf16s(a.x); v[1] = f2bf16s(a.y);
        v[2] = f2bf16s(a.z); v[3] = f2bf16s(a.w);
        v[4] = f2bf16s(b.x); v[5] = f2bf16s(b.y);
        v[6] = f2bf16s(b.z); v[7] = f2bf16s(b.w);
        *(bf16x8*)dst = v;
    }
}

// ================= K2: xproj -> CONSUMER-ORDER layout (fp32) ==============
// xpp dword addr: ((t*128 + bid)*8 + wave)*512 + (lgrp*16 + l)*8 + half*4 + r
// so each K3 lane reads ONE contiguous 32B (acc00[0..3], acc01[0..3]).
__global__ __launch_bounds__(256)
void xproj_gemm(const unsigned short* __restrict__ xbf,
                const unsigned short* __restrict__ Wbf,
                float* __restrict__ xpp) {
    const int tid = threadIdx.x;
    const int w = tid >> 6;
    const int lane = tid & 63;
    const int ln15 = lane & 15;
    const int lgrp = lane >> 4;
    const int k8 = lgrp * 8;
    const int m0 = blockIdx.x * 128 + w * 32 + ln15;   // A rows (m0, m0+16); t = blockIdx.x
    const int n0 = blockIdx.y * 128 + ln15;            // B rows n0 + nt*16

    f32x4 acc[2][8];
    #pragma unroll
    for (int i = 0; i < 2; i++)
        #pragma unroll
        for (int j = 0; j < 8; j++) acc[i][j] = (f32x4){0.f, 0.f, 0.f, 0.f};

    #pragma unroll 4
    for (int kt = 0; kt < INP / 32; kt++) {
        const int k = kt * 32 + k8;
        bf16x8 a0 = *(const bf16x8*)(xbf + (size_t)m0 * INP + k);
        bf16x8 a1 = *(const bf16x8*)(xbf + (size_t)(m0 + 16) * INP + k);
        #pragma unroll
        for (int nt = 0; nt < 8; nt++) {
            bf16x8 b = *(const bf16x8*)(Wbf + (size_t)(n0 + nt * 16) * INP + k);
            acc[0][nt] = __builtin_amdgcn_mfma_f32_16x16x32_bf16(a0, b, acc[0][nt], 0, 0, 0);
            acc[1][nt] = __builtin_amdgcn_mfma_f32_16x16x32_bf16(a1, b, acc[1][nt], 0, 0, 0);
        }
    }
    // scatter into consumer order; acc[mi][nt][r] has r = batch&3 contiguous
    #pragma unroll
    for (int nt = 0; nt < 8; nt++) {
        const int n = blockIdx.y * 128 + nt * 16 + ln15;
        const int bid3 = (n & 1023) >> 3;
        const int half = n >> 11;
        const int l3 = (n & 7) | (((n >> 10) & 1) << 3);
        #pragma unroll
        for (int mi = 0; mi < 2; mi++) {
            const int w3 = w * 2 + mi;
            size_t base = (((size_t)blockIdx.x * 128 + bid3) * 8 + w3) * 512
                        + (size_t)(lgrp * 16 + l3) * 8 + half * 4;
            *(float4*)(xpp + base) = *(float4*)&acc[mi][nt];
        }
    }
}

// ================= K3: recurrent loop (cooperative) =======================
__device__ __forceinline__ void bar_signal(unsigned* flags, int bid, unsigned val) {
    __hip_atomic_store(&flags[bid], val, __ATOMIC_RELAXED,
                       __HIP_MEMORY_SCOPE_AGENT);
}
// ring mode: per-chunk wait (32 producer flags), no fence (never-reused addrs)
__device__ __forceinline__ void wait_chunk(const unsigned* flags, int c, int lane,
                                           unsigned want) {
    const unsigned* p = &flags[c * 32 + (lane & 31)];
    for (;;) {
        unsigned f = __hip_atomic_load(p, __ATOMIC_RELAXED,
                                       __HIP_MEMORY_SCOPE_AGENT);
        if (__all(f >= want)) break;
        __builtin_amdgcn_s_sleep(1);
    }
    asm volatile("" ::: "memory");   // forbid hoisting h-loads above the poll
}
// dbuf fallback: monolithic wait + acquire-inv (R6-proven)
__device__ __forceinline__ void bar_wait_all(const unsigned* flags, int lane,
                                             unsigned want) {
    const unsigned* p0 = &flags[lane];
    const unsigned* p1 = &flags[64 + lane];
    for (;;) {
        unsigned f0 = __hip_atomic_load(p0, __ATOMIC_RELAXED,
                                        __HIP_MEMORY_SCOPE_AGENT);
        unsigned f1 = __hip_atomic_load(p1, __ATOMIC_RELAXED,
                                        __HIP_MEMORY_SCOPE_AGENT);
        if (__all((f0 >= want) && (f1 >= want))) break;
        __builtin_amdgcn_s_sleep(1);
    }
    __builtin_amdgcn_fence(__ATOMIC_ACQUIRE, "agent");
}

__global__ __launch_bounds__(NTHR)
void lstm_fused(const float* __restrict__ x,
                const float* __restrict__ W_ih,
                const float* __restrict__ W_hh,
                const float* __restrict__ b_ih,
                const float* __restrict__ b_hh,
                const float* __restrict__ W_fc,
                const float* __restrict__ b_fc,
                float* __restrict__ out,
                unsigned short* __restrict__ h0,
                unsigned short* __restrict__ h1,
                unsigned short* __restrict__ xbf,
                const float* __restrict__ xpp,
                unsigned short* __restrict__ ring,
                int use_xbf, int use_xp, int use_ring,
                unsigned* __restrict__ flags)
{
    __shared__ short W_sw[2 * NKT * 64 * 8];   // 98304 B, MFMA-fragment order
    __shared__ float gw[8][16][33];            // per-wave gate transpose
    __shared__ unsigned wcnt;                  // producer completion counter

    const int tid = threadIdx.x;
    const int bid = blockIdx.x;
    const int j0 = bid * BJ;

    // ---------------- one-time init ----------------
    for (int f = tid; f < 2 * NKT * 64; f += NTHR) {
        const int ln = f & 63;
        const int kt = (f >> 6) % NKT;
        const int nt = f / (NKT * 64);
        const int n = nt * 16 + (ln & 15);
        const int r = (n >> 3) * HID + j0 + (n & 7);
        const int kbase = kt * 32 + (ln >> 4) * 8;
        short tmp[8];
        #pragma unroll
        for (int j = 0; j < 8; j++) {
            const int k = kbase + j;
            float w = (k < INP) ? W_ih[(size_t)r * INP + k]
                                : W_hh[(size_t)r * HID + (k - INP)];
            tmp[j] = f2bf16s(w);
        }
        *(bf16x8*)&W_sw[(size_t)f * 8] = *(bf16x8*)tmp;
    }
    {   // zero h0 (dbuf start) and ring buffer 0 (perm(0)=0): 65536 dwords each
        const unsigned g = (unsigned)bid * NTHR + tid;
        ((unsigned*)h0)[g] = 0u;
        if (use_ring) ((unsigned*)ring)[g] = 0u;
    }
    if (bid == 0) {
        for (int i = tid; i < NBLK; i += NTHR) flags[i] = 0u;
    }
    if (tid == 0) wcnt = 0u;
    if (use_xbf) {
        const size_t total8 = (size_t)SEQ * BATCH * INP / 8;
        for (size_t c = (size_t)bid * NTHR + tid; c < total8;
             c += (size_t)NBLK * NTHR) {
            const float* src = x + c * 8;
            const float4 a = *(const float4*)src;
            const float4 b = *(const float4*)(src + 4);
            bf16x8 v;
            v[0] = f2bf16s(a.x); v[1] = f2bf16s(a.y);
            v[2] = f2bf16s(a.z); v[3] = f2bf16s(a.w);
            v[4] = f2bf16s(b.x); v[5] = f2bf16s(b.y);
            v[6] = f2bf16s(b.z); v[7] = f2bf16s(b.w);
            *(bf16x8*)(xbf + c * 8) = v;
        }
    }

    const int wave = tid >> 6;
    const int lane = tid & 63;
    const int ln15 = lane & 15;
    const int lgrp = lane >> 4;
    const int arow = wave * 16 + ln15;
    const int k8 = lgrp * 8;

    // cell-update assignment: 2 cells/thread
    const int crow = lane >> 2;
    const int cp   = (lane & 3) * 2;
    const int bg   = wave * 16 + crow;
    float c_r[2] = {0.f, 0.f};
    float bias_r[2][4];
    #pragma unroll
    for (int jj = 0; jj < 2; jj++)
        #pragma unroll
        for (int g = 0; g < 4; g++) {
            const int r = g * HID + j0 + cp + jj;
            bias_r[jj][g] = b_ih[r] + b_hh[r];
        }
    // xpp scatter indices (fallback when !use_xp uses in-loop x-GEMM)
    const int nA = ((ln15 >> 3) * HID) + j0 + (ln15 & 7);
    const int nB = (((16 + ln15) >> 3) * HID) + j0 + (ln15 & 7);
    (void)nA; (void)nB;

    __syncthreads();
    cg::this_grid().sync();   // release init writes (zeros, xbf) grid-wide

    const bf16x8* Wl = (const bf16x8*)W_sw + lane;

    if (use_ring && use_xp) {
        // ========== fence-free ring path: no __syncthreads in loop ==========
        const int crot = (bid >> 5) & 3;
        const int myck = bid >> 5;               // chunk this block produces
        const int mycol = (bid & 31) * 8 + cp;   // within-chunk h column
        for (int t = 0; t < SEQ; t++) {
            const unsigned short* hb = ring + (size_t)permbuf(t) * (BATCH * HID);
            unsigned short* hn = ring + (size_t)permbuf(t + 1) * (BATCH * HID);

            // xpp prefetch (consumed at end of step -> fully hidden)
            const float* xvp = xpp + (((size_t)t * NBLK + bid) * 8 + wave) * 512
                                   + (size_t)(lgrp * 16 + ln15) * 8;
            const float4 xv0 = *(const float4*)xvp;
            const float4 xv1 = *(const float4*)(xvp + 4);

            f32x4 acc00 = {0.f,0.f,0.f,0.f}, acc01 = {0.f,0.f,0.f,0.f};

            #pragma unroll
            for (int cc = 0; cc < 4; cc++) {
                const int c = (cc + crot) & 3;
                wait_chunk(flags, c, lane, (unsigned)t);
                // chunk-major ring layout: [chunk][BATCH][256]
                const unsigned short* hc8 =
                    hb + ((size_t)c * BATCH + arow) * 256 + k8;
                #pragma unroll
                for (int q = 0; q < 8; q++) {
                    const int kt = c * 8 + q;
                    bf16x8 a  = *(const bf16x8*)(hc8 + q * 32);
                    bf16x8 b0 = Wl[(NKX + kt) * 64];
                    bf16x8 b1 = Wl[(NKT + NKX + kt) * 64];
                    acc00 = __builtin_amdgcn_mfma_f32_16x16x32_bf16(a, b0, acc00, 0, 0, 0);
                    acc01 = __builtin_amdgcn_mfma_f32_16x16x32_bf16(a, b1, acc01, 0, 0, 0);
                }
            }
            // add precomputed x-projection
            acc00[0] += xv0.x; acc00[1] += xv0.y; acc00[2] += xv0.z; acc00[3] += xv0.w;
            acc01[0] += xv1.x; acc01[1] += xv1.y; acc01[2] += xv1.z; acc01[3] += xv1.w;

            // wave-private transpose
            {
                const int r0 = lgrp * 4;
                #pragma unroll
                for (int r = 0; r < 4; r++) {
                    gw[wave][r0 + r][ln15]      = acc00[r];
                    gw[wave][r0 + r][16 + ln15] = acc01[r];
                }
            }
            // cell update (2 cells) + packed 4B store to next ring buffer
            {
                unsigned pack = 0;
                #pragma unroll
                for (int jj = 0; jj < 2; jj++) {
                    const int dj = cp + jj;
                    float ig = gw[wave][crow][dj]      + bias_r[jj][0];
                    float fg = gw[wave][crow][8 + dj]  + bias_r[jj][1];
                    float gg = gw[wave][crow][16 + dj] + bias_r[jj][2];
                    float og = gw[wave][crow][24 + dj] + bias_r[jj][3];
                    ig = sigmoidf_(ig); fg = sigmoidf_(fg);
                    gg = tanhf_(gg);    og = sigmoidf_(og);
                    float c = fg * c_r[jj] + ig * gg;
                    c_r[jj] = c;
                    float h = og * tanhf_(c);
                    pack |= ((unsigned)(unsigned short)f2bf16s(h)) << (16 * jj);
                }
                __hip_atomic_store(
                    (unsigned*)(hn + ((size_t)myck * BATCH + bg) * 256 + mycol),
                    pack, __ATOMIC_RELAXED, __HIP_MEMORY_SCOPE_AGENT);
            }
            asm volatile("s_waitcnt vmcnt(0)" ::: "memory");  // wave's h acked at L3
            if (lane == 0) {
                unsigned old = atomicAdd(&wcnt, 1u);
                if (old == 8u * (unsigned)(t + 1) - 1u)
                    bar_signal(flags, bid, (unsigned)(t + 1));
            }
        }
    } else {
        // ========== dbuf fallback (R6-proven structure) ==========
        for (int t = 0; t < SEQ; t++) {
            const unsigned short* __restrict__ hp = (t & 1) ? h1 : h0;
            unsigned short* __restrict__ hcur     = (t & 1) ? h0 : h1;
            f32x4 acc00 = {0.f,0.f,0.f,0.f}, acc01 = {0.f,0.f,0.f,0.f};
            float4 xv0 = {0,0,0,0}, xv1 = {0,0,0,0};

            if (use_xp) {
                const float* xvp = xpp + (((size_t)t * NBLK + bid) * 8 + wave) * 512
                                       + (size_t)(lgrp * 16 + ln15) * 8;
                xv0 = *(const float4*)xvp;
                xv1 = *(const float4*)(xvp + 4);
            } else if (use_xbf) {
                const unsigned short* xr =
                    xbf + (size_t)t * (BATCH * INP) + (size_t)arow * INP + k8;
                #pragma unroll
                for (int kt = 0; kt < NKX; kt++) {
                    bf16x8 a  = *(const bf16x8*)(xr + kt * 32);
                    bf16x8 b0 = Wl[kt * 64];
                    bf16x8 b1 = Wl[(NKT + kt) * 64];
                    acc00 = __builtin_amdgcn_mfma_f32_16x16x32_bf16(a, b0, acc00, 0, 0, 0);
                    acc01 = __builtin_amdgcn_mfma_f32_16x16x32_bf16(a, b1, acc01, 0, 0, 0);
                }
            } else {
                const float* xr =
                    x + (size_t)t * (BATCH * INP) + (size_t)arow * INP + k8;
                #pragma unroll
                for (int kt = 0; kt < NKX; kt++) {
                    const float4 xa = *(const float4*)(xr + kt * 32);
                    const float4 xb = *(const float4*)(xr + kt * 32 + 4);
                    bf16x8 a;
                    a[0]=f2bf16s(xa.x); a[1]=f2bf16s(xa.y); a[2]=f2bf16s(xa.z); a[3]=f2bf16s(xa.w);
                    a[4]=f2bf16s(xb.x); a[5]=f2bf16s(xb.y); a[6]=f2bf16s(xb.z); a[7]=f2bf16s(xb.w);
                    bf16x8 b0 = Wl[kt * 64];
                    bf16x8 b1 = Wl[(NKT + kt) * 64];
                    acc00 = __builtin_amdgcn_mfma_f32_16x16x32_bf16(a, b0, acc00, 0, 0, 0);
                    acc01 = __builtin_amdgcn_mfma_f32_16x16x32_bf16(a, b1, acc01, 0, 0, 0);
                }
            }

            if (tid < 64) bar_wait_all(flags, lane, (unsigned)t);
            __syncthreads();

            {
                const unsigned short* hr = hp + (size_t)arow * HID + k8;
                #pragma unroll
                for (int kt = 0; kt < NKH; kt++) {
                    bf16x8 a  = *(const bf16x8*)(hr + kt * 32);
                    bf16x8 b0 = Wl[(NKX + kt) * 64];
                    bf16x8 b1 = Wl[(NKT + NKX + kt) * 64];
                    acc00 = __builtin_amdgcn_mfma_f32_16x16x32_bf16(a, b0, acc00, 0, 0, 0);
                    acc01 = __builtin_amdgcn_mfma_f32_16x16x32_bf16(a, b1, acc01, 0, 0, 0);
                }
            }
            acc00[0] += xv0.x; acc00[1] += xv0.y; acc00[2] += xv0.z; acc00[3] += xv0.w;
            acc01[0] += xv1.x; acc01[1] += xv1.y; acc01[2] += xv1.z; acc01[3] += xv1.w;
            {
                const int r0 = lgrp * 4;
                #pragma unroll
                for (int r = 0; r < 4; r++) {
                    gw[wave][r0 + r][ln15]      = acc00[r];
                    gw[wave][r0 + r][16 + ln15] = acc01[r];
                }
            }
            {
                unsigned pack = 0;
                #pragma unroll
                for (int jj = 0; jj < 2; jj++) {
                    const int dj = cp + jj;
                    float ig = gw[wave][crow][dj]      + bias_r[jj][0];
                    float fg = gw[wave][crow][8 + dj]  + bias_r[jj][1];
                    float gg = gw[wave][crow][16 + dj] + bias_r[jj][2];
                    float og = gw[wave][crow][24 + dj] + bias_r[jj][3];
                    ig = sigmoidf_(ig); fg = sigmoidf_(fg);
                    gg = tanhf_(gg);    og = sigmoidf_(og);
                    float c = fg * c_r[jj] + ig * gg;
                    c_r[jj] = c;
                    float h = og * tanhf_(c);
                    pack |= ((unsigned)(unsigned short)f2bf16s(h)) << (16 * jj);
                }
                __hip_atomic_store((unsigned*)(hcur + (size_t)bg * HID + j0 + cp),
                                   pack, __ATOMIC_RELAXED, __HIP_MEMORY_SCOPE_AGENT);
            }
            asm volatile("s_waitcnt vmcnt(0)" ::: "memory");
            __syncthreads();
            if (tid == 0) bar_signal(flags, bid, (unsigned)(t + 1));
        }
    }

    cg::this_grid().sync();   // full release/acquire before epilogue

    // ---- FC epilogue ----
    const unsigned short* hl = (use_ring && use_xp) ? ring : h0;  // perm(512)=0
    const int ringmode = (use_ring && use_xp) ? 1 : 0;
    for (unsigned idx = (unsigned)bid * NTHR + tid; idx < BATCH * CLASSES;
         idx += (unsigned)NBLK * NTHR) {
        const int b   = idx / CLASSES;
        const int cls = idx % CLASSES;
        const float* wrow = W_fc + (size_t)cls * HID;
        float acc = 0.f;
        #pragma unroll 4
        for (int k = 0; k < HID; k += 8) {
            const unsigned short* hp8 = ringmode
                ? (hl + ((size_t)(k >> 8) * BATCH + b) * 256 + (k & 255))
                : (hl + (size_t)b * HID + k);
            bf16x8 hv = *(const bf16x8*)hp8;
            float4 w0 = *(const float4*)(wrow + k);
            float4 w1 = *(const float4*)(wrow + k + 4);
            union { unsigned u; float f; } e;
            float s = 0.f;
            e.u = ((unsigned)(unsigned short)hv[0]) << 16; s += e.f * w0.x;
            e.u = ((unsigned)(unsigned short)hv[1]) << 16; s += e.f * w0.y;
            e.u = ((unsigned)(unsigned short)hv[2]) << 16; s += e.f * w0.z;
            e.u = ((unsigned)(unsigned short)hv[3]) << 16; s += e.f * w0.w;
            e.u = ((unsigned)(unsigned short)hv[4]) << 16; s += e.f * w1.x;
            e.u = ((unsigned)(unsigned short)hv[5]) << 16; s += e.f * w1.y;
            e.u = ((unsigned)(unsigned short)hv[6]) << 16; s += e.f * w1.z;
            e.u = ((unsigned)(unsigned short)hv[7]) << 16; s += e.f * w1.w;
            acc += s;
        }
        out[idx] = acc + b_fc[cls];
    }
}

extern "C" void kernel_launch(void* const* d_in, const int* in_sizes, int n_in,
                              void* d_out, int out_size, void* d_ws, size_t ws_size,
                              hipStream_t stream) {
    const float* x    = (const float*)d_in[0];
    const float* W_ih = (const float*)d_in[1];
    const float* W_hh = (const float*)d_in[2];
    const float* b_ih = (const float*)d_in[3];
    const float* b_hh = (const float*)d_in[4];
    const float* W_fc = (const float*)d_in[5];
    const float* b_fc = (const float*)d_in[6];
    float* out = (float*)d_out;

    // ws layout: h0 | h1 | xbf(64MB) | Wbf(4MB) | xpp(1GB) | ring(128MB)
    const size_t OFF_H1   = (size_t)BATCH * HID * 2;
    const size_t OFF_XBF  = 2 * OFF_H1;
    const size_t XBF_B    = (size_t)SEQ * BATCH * INP * 2;
    const size_t OFF_WBF  = OFF_XBF + XBF_B;
    const size_t WBF_B    = (size_t)4 * HID * INP * 2;
    const size_t OFF_XPP  = OFF_WBF + WBF_B;
    const size_t XPP_B    = (size_t)SEQ * BATCH * G4H * 4;
    const size_t OFF_RING = OFF_XPP + XPP_B;
    const size_t RING_B   = (size_t)512 * BATCH * HID * 2;

    unsigned short* h0   = (unsigned short*)d_ws;
    unsigned short* h1   = (unsigned short*)((char*)d_ws + OFF_H1);
    unsigned short* xbf  = (unsigned short*)((char*)d_ws + OFF_XBF);
    unsigned short* Wbf  = (unsigned short*)((char*)d_ws + OFF_WBF);
    float*          xpp  = (float*)((char*)d_ws + OFF_XPP);
    unsigned short* ring = (unsigned short*)((char*)d_ws + OFF_RING);

    int use_xbf  = (ws_size >= OFF_XBF + XBF_B) ? 1 : 0;
    int use_xp   = (ws_size >= OFF_XPP + XPP_B) ? 1 : 0;
    int use_ring = (ws_size >= OFF_RING + RING_B) ? 1 : 0;

    if (use_xbf) {
        convert_bf16<<<dim3(2048), dim3(256), 0, stream>>>(x, W_ih, xbf, Wbf, use_xp);
    }
    if (use_xp) {
        xproj_gemm<<<dim3(512, 32), dim3(256), 0, stream>>>(xbf, Wbf, xpp);
    }

    unsigned* flags = (unsigned*)d_out;  // 128 words; overwritten by FC at end

    void* args[] = {&x, &W_ih, &W_hh, &b_ih, &b_hh, &W_fc, &b_fc, &out,
                    &h0, &h1, &xbf, &xpp, &ring, &use_xbf, &use_xp, &use_ring,
                    &flags};
    hipLaunchCooperativeKernel((void*)lstm_fused, dim3(NBLK), dim3(NTHR),
                               args, 0, stream);
}